// Round 7
// baseline (252.634 us; speedup 1.0000x reference)
//
#include <hip/hip_runtime.h>
#include <hip/hip_bf16.h>
#include <math.h>

#define NTOK 16384
#define DDIM 1024
#define HALF 512
#define SUB  512
#define KDIM 512
#define TOPK 8
#define NCAND 16
#define VDIM 128

typedef __attribute__((ext_vector_type(8))) short bf16x8;
typedef __attribute__((ext_vector_type(4))) float f32x4;

static __device__ __forceinline__ unsigned short f2bf(float x) {
    union { float f; unsigned u; } v; v.f = x;
    unsigned r = v.u + 0x7FFF + ((v.u >> 16) & 1);   // RNE
    return (unsigned short)(r >> 16);
}

static __device__ __forceinline__ void split_bf(float x, unsigned short& h, unsigned short& l) {
    h = f2bf(x);
    union { unsigned u; float f; } hv; hv.u = ((unsigned)h) << 16;
    l = f2bf(x - hv.f);
}

// ---------------------------------------------------------------------------
// Kernel 0: codebooks -> packed hi/lo bf16 MFMA-B-fragment stream:
//   Bp[half][cq(4)][step s=kc*8+nt][{hi 1KB, lo 1KB}], frag elem:
//   n = cq*128 + nt*16 + (lane&15), k = kc*32 + (lane>>4)*8 + j
// ---------------------------------------------------------------------------
__global__ __launch_bounds__(256)
void cvt_bfrag(const float* __restrict__ cb1, const float* __restrict__ cb2,
               char* __restrict__ Bp)
{
    int fid  = blockIdx.x * 256 + threadIdx.x;   // 0..65535
    int lane = fid & 63;
    int nt   = (fid >> 6) & 7;
    int kc   = (fid >> 9) & 15;
    int cq   = (fid >> 13) & 3;
    int hf   = (fid >> 15) & 1;
    const float* cb = hf ? cb2 : cb1;
    int n  = cq * 128 + nt * 16 + (lane & 15);
    int kb = kc * 32 + (lane >> 4) * 8;
    const float* src = cb + (size_t)n * KDIM + kb;
    float4 f0 = *(const float4*)src;
    float4 f1 = *(const float4*)(src + 4);
    unsigned short hh[8], ll[8];
    split_bf(f0.x, hh[0], ll[0]); split_bf(f0.y, hh[1], ll[1]);
    split_bf(f0.z, hh[2], ll[2]); split_bf(f0.w, hh[3], ll[3]);
    split_bf(f1.x, hh[4], ll[4]); split_bf(f1.y, hh[5], ll[5]);
    split_bf(f1.z, hh[6], ll[6]); split_bf(f1.w, hh[7], ll[7]);
    size_t dst = ((size_t)(hf * 4 + cq) * 128 + (kc * 8 + nt)) * 2048 + lane * 16;
    *(int4*)(Bp + dst)        = *(const int4*)hh;
    *(int4*)(Bp + dst + 1024) = *(const int4*)ll;
}

// ---------------------------------------------------------------------------
// Kernel 1a: pure score GEMM. Block = 16 tokens x one half, 4 waves
// (wave = cand quarter). A: fp32->bf16 hi/lo in 32 KB swizzled LDS.
// B: packed stream global->register, full-ring term-major consumption:
//   T1=(ah,rh[*]), T3=(al,rh[*]) (+reload rh), T2=(ah,rl[*]) (+reload rl)
// -> same-acc MFMA distance 8, load-to-use ~15 MFMAs. Writes fp32 scores.
// ---------------------------------------------------------------------------
__global__ __launch_bounds__(256, 2)
void score_gemm(const float* __restrict__ query,
                const char* __restrict__ Bp,
                float* __restrict__ scores)
{
    __shared__ char smem[32768];
    char* sAh = smem;            // bf16 [16][512] swizzled (16B chunks XOR row&7)
    char* sAl = smem + 16384;

    const int tid  = threadIdx.x;
    const int hf   = blockIdx.y;
    const int tok0 = blockIdx.x * 16;
    const int qoff = hf * HALF;

    const int lane = tid & 63;
    const int wid  = tid >> 6;          // 0..3 = cand quarter
    const int l15  = lane & 15;
    const int lh   = lane >> 4;
    const int l7   = lane & 7;

    // ---- stage A: 16 tok x 512 k fp32 -> bf16 hi/lo, swizzled LDS ----
    #pragma unroll
    for (int i = 0; i < 4; i++) {
        int c   = i * 256 + tid;        // 0..1023 16B-chunks
        int row = c >> 6;
        int b8  = c & 63;
        const float* src = query + (size_t)(tok0 + row) * DDIM + qoff + b8 * 8;
        float4 f0 = *(const float4*)(src);
        float4 f1 = *(const float4*)(src + 4);
        unsigned short hh[8], ll[8];
        split_bf(f0.x, hh[0], ll[0]); split_bf(f0.y, hh[1], ll[1]);
        split_bf(f0.z, hh[2], ll[2]); split_bf(f0.w, hh[3], ll[3]);
        split_bf(f1.x, hh[4], ll[4]); split_bf(f1.y, hh[5], ll[5]);
        split_bf(f1.z, hh[6], ll[6]); split_bf(f1.w, hh[7], ll[7]);
        int boff = row * 1024 + ((b8 * 16) ^ ((row & 7) << 4));
        *(int4*)(sAh + boff) = *(const int4*)hh;
        *(int4*)(sAl + boff) = *(const int4*)ll;
    }
    __syncthreads();

    // ---- B stream: ring holds current kc's 8 nt fragments (hi+lo) ----
    const char* bp = Bp + (size_t)(hf * 4 + wid) * 262144 + lane * 16;

    int4 rh[8], rl[8];
    #pragma unroll
    for (int p = 0; p < 8; p++) {
        rh[p] = *(const int4*)(bp + p * 2048);
        rl[p] = *(const int4*)(bp + p * 2048 + 1024);
    }

    f32x4 acc[8];
    #pragma unroll
    for (int nt = 0; nt < 8; nt++) acc[nt] = (f32x4){0.f, 0.f, 0.f, 0.f};

    for (int kc = 0; kc < 16; kc++) {
        const int co = (kc * 64 + lh * 16) ^ (l7 << 4);
        const bf16x8 ah = *(const bf16x8*)(sAh + l15 * 1024 + co);
        const bf16x8 al = *(const bf16x8*)(sAl + l15 * 1024 + co);
        const int nb = ((kc + 1) & 15) * 8;          // next kc's step base

        // T1: hi x hi
        #pragma unroll
        for (int nt = 0; nt < 8; nt++) {
            union { int4 i; bf16x8 b; } u; u.i = rh[nt];
            acc[nt] = __builtin_amdgcn_mfma_f32_16x16x32_bf16(ah, u.b, acc[nt], 0, 0, 0);
        }
        // T3: lo x hi  (rh[nt] dead afterwards -> reload for next kc)
        #pragma unroll
        for (int nt = 0; nt < 8; nt++) {
            union { int4 i; bf16x8 b; } u; u.i = rh[nt];
            rh[nt] = *(const int4*)(bp + (nb + nt) * 2048);
            acc[nt] = __builtin_amdgcn_mfma_f32_16x16x32_bf16(al, u.b, acc[nt], 0, 0, 0);
        }
        // T2: hi x lo  (rl[nt] dead afterwards -> reload for next kc)
        #pragma unroll
        for (int nt = 0; nt < 8; nt++) {
            union { int4 i; bf16x8 b; } u; u.i = rl[nt];
            rl[nt] = *(const int4*)(bp + (nb + nt) * 2048 + 1024);
            acc[nt] = __builtin_amdgcn_mfma_f32_16x16x32_bf16(ah, u.b, acc[nt], 0, 0, 0);
        }
    }

    // ---- C-write: token = tok0 + lh*4 + r, col = wid*128 + nt*16 + l15 ----
    #pragma unroll
    for (int nt = 0; nt < 8; nt++)
        #pragma unroll
        for (int r = 0; r < 4; r++) {
            int t = tok0 + lh * 4 + r;
            int c = hf * 512 + wid * 128 + nt * 16 + l15;
            scores[((size_t)t << 10) + c] = acc[nt][r];
        }
}

// ---------------------------------------------------------------------------
// Kernel 1b: top-k. One wave per (token, half): bisect+gate fast path,
// fp64-rescore slow path for ambiguous tokens (proven R2-R6).
// ---------------------------------------------------------------------------
__global__ __launch_bounds__(256)
void topk_kernel(const float* __restrict__ scores,
                 const float* __restrict__ query,
                 const float* __restrict__ cb1f,
                 const float* __restrict__ cb2f,
                 int*   __restrict__ tk_idx,
                 float* __restrict__ tk_val)
{
    const int tid  = threadIdx.x;
    const int lane = tid & 63;
    const int gid  = blockIdx.x * 4 + (tid >> 6);
    const int tok  = gid >> 1;
    const int hf   = gid & 1;
    const float* __restrict__ cbf = hf ? cb2f : cb1f;
    const int qoff = hf * HALF;

    float sv[8];
    #pragma unroll
    for (int j = 0; j < 8; j++)
        sv[j] = scores[((size_t)tok << 10) + hf * 512 + lane + 64 * j];

    float m = sv[0];
    #pragma unroll
    for (int j = 1; j < 8; j++) m = fmaxf(m, sv[j]);
    #pragma unroll
    for (int off = 32; off > 0; off >>= 1) m = fmaxf(m, __shfl_xor(m, off));

    auto wave_cnt = [&](float tau) -> int {
        int c = 0;
        #pragma unroll
        for (int j = 0; j < 8; j++)
            c += __popcll(__ballot(sv[j] > tau));
        return c;
    };

    float lo = m - 0.5f, hi = m;
    while (wave_cnt(lo) < 9) lo -= 0.5f;
    for (int it = 0; it < 14; it++) {
        float mid = 0.5f * (lo + hi);
        if (wave_cnt(mid) >= 9) lo = mid; else hi = mid;
    }
    int ch8 = wave_cnt(hi);

    float v8 = 1e30f, v9 = -1e30f;
    #pragma unroll
    for (int j = 0; j < 8; j++) {
        bool sel = sv[j] > hi;
        v8 = sel ? fminf(v8, sv[j]) : v8;
        v9 = sel ? v9 : fmaxf(v9, sv[j]);
    }
    #pragma unroll
    for (int off = 32; off > 0; off >>= 1) {
        v8 = fminf(v8, __shfl_xor(v8, off));
        v9 = fmaxf(v9, __shfl_xor(v9, off));
    }

    if (ch8 == 8 && (v8 - v9) > 6e-5f) {
        int base = 0;
        #pragma unroll
        for (int j = 0; j < 8; j++) {
            unsigned long long mk = __ballot(sv[j] > hi);
            if (sv[j] > hi) {
                int pos = base + __popcll(mk & ((1ULL << lane) - 1ULL));
                tk_idx[((size_t)tok * 2 + hf) * TOPK + pos] = lane + 64 * j;
                tk_val[((size_t)tok * 2 + hf) * TOPK + pos] = sv[j];
            }
            base += __popcll(mk);
        }
    } else {
        // slow path (rare): coarse top-16 + fp64 rescore, exact ordering
        int cand[NCAND];
        #pragma unroll
        for (int r = 0; r < NCAND; r++) {
            float bv = sv[0]; int bj = 0;
            #pragma unroll
            for (int j = 1; j < 8; j++) if (sv[j] > bv) { bv = sv[j]; bj = j; }
            int bidx = lane + 64 * bj;
            #pragma unroll
            for (int off = 32; off > 0; off >>= 1) {
                float ov = __shfl_xor(bv, off);
                int   oi = __shfl_xor(bidx, off);
                if (ov > bv || (ov == bv && oi < bidx)) { bv = ov; bidx = oi; }
            }
            cand[r] = bidx;
            int jj = bidx >> 6;
            if ((bidx & 63) == lane) {
                #pragma unroll
                for (int j = 0; j < 8; j++) if (j == jj) sv[j] = -INFINITY;
            }
        }
        double qd[8];
        #pragma unroll
        for (int j = 0; j < 8; j++)
            qd[j] = (double)query[(size_t)tok * DDIM + qoff + lane + 64 * j];
        double rv[NCAND];
        #pragma unroll
        for (int r = 0; r < NCAND; r++) {
            const float* __restrict__ crow = &cbf[(size_t)cand[r] * KDIM];
            double a = 0.0;
            #pragma unroll
            for (int j = 0; j < 8; j++)
                a = fma(qd[j], (double)crow[lane + 64 * j], a);
            #pragma unroll
            for (int off = 32; off > 0; off >>= 1)
                a += __shfl_xor(a, off);
            rv[r] = a;
        }
        if (lane == 0) {
            #pragma unroll
            for (int r = 0; r < NCAND; r++) {
                int rk = 0;
                #pragma unroll
                for (int mm = 0; mm < NCAND; mm++)
                    if (rv[mm] > rv[r] || (rv[mm] == rv[r] && cand[mm] < cand[r])) rk++;
                if (rk < TOPK) {
                    tk_idx[((size_t)tok * 2 + hf) * TOPK + rk] = cand[r];
                    tk_val[((size_t)tok * 2 + hf) * TOPK + rk] = (float)rv[r];
                }
            }
        }
    }
}

// ---------------------------------------------------------------------------
// Fallback fused kernel (R6, proven): used only if ws_size < 68 MB.
// ---------------------------------------------------------------------------
__global__ __launch_bounds__(256, 2)
void score_topk_fused(const float* __restrict__ query,
                      const float* __restrict__ cb1f,
                      const float* __restrict__ cb2f,
                      const char* __restrict__ Bp,
                      int*   __restrict__ tk_idx,
                      float* __restrict__ tk_val)
{
    __shared__ char smem[65536];
    char* sAh = smem;
    char* sAl = smem + 32768;
    float* sS = (float*)smem;

    const int tid  = threadIdx.x;
    const int hf   = blockIdx.y;
    const int tok0 = blockIdx.x * 32;
    const float* __restrict__ cbf = hf ? cb2f : cb1f;
    const int qoff = hf * HALF;

    const int lane = tid & 63;
    const int wid  = tid >> 6;
    const int l15  = lane & 15;
    const int lh   = lane >> 4;
    const int l7   = lane & 7;

    #pragma unroll
    for (int i = 0; i < 8; i++) {
        int c   = i * 256 + tid;
        int row = c >> 6;
        int b8  = c & 63;
        const float* src = query + (size_t)(tok0 + row) * DDIM + qoff + b8 * 8;
        float4 f0 = *(const float4*)(src);
        float4 f1 = *(const float4*)(src + 4);
        unsigned short hh[8], ll[8];
        split_bf(f0.x, hh[0], ll[0]); split_bf(f0.y, hh[1], ll[1]);
        split_bf(f0.z, hh[2], ll[2]); split_bf(f0.w, hh[3], ll[3]);
        split_bf(f1.x, hh[4], ll[4]); split_bf(f1.y, hh[5], ll[5]);
        split_bf(f1.z, hh[6], ll[6]); split_bf(f1.w, hh[7], ll[7]);
        int boff = row * 1024 + ((b8 * 16) ^ ((row & 7) << 4));
        *(int4*)(sAh + boff) = *(const int4*)hh;
        *(int4*)(sAl + boff) = *(const int4*)ll;
    }
    __syncthreads();

    const char* bp = Bp + (size_t)(hf * 4 + wid) * 262144 + lane * 16;
    int4 rh[8], rl[8];
    #pragma unroll
    for (int p = 0; p < 8; p++) {
        rh[p] = *(const int4*)(bp + p * 2048);
        rl[p] = *(const int4*)(bp + p * 2048 + 1024);
    }

    f32x4 acc[2][8];
    #pragma unroll
    for (int tg = 0; tg < 2; tg++)
        #pragma unroll
        for (int nt = 0; nt < 8; nt++) acc[tg][nt] = (f32x4){0.f, 0.f, 0.f, 0.f};

    for (int kc = 0; kc < 16; kc++) {
        const int co = (kc * 64 + lh * 16) ^ (l7 << 4);
        const bf16x8 ah0 = *(const bf16x8*)(sAh + l15 * 1024 + co);
        const bf16x8 al0 = *(const bf16x8*)(sAl + l15 * 1024 + co);
        const bf16x8 ah1 = *(const bf16x8*)(sAh + (16 + l15) * 1024 + co);
        const bf16x8 al1 = *(const bf16x8*)(sAl + (16 + l15) * 1024 + co);
        #pragma unroll
        for (int nt = 0; nt < 8; nt++) {
            union { int4 i; bf16x8 b; } ubh, ubl;
            ubh.i = rh[nt]; ubl.i = rl[nt];
            const int sp = (kc * 8 + nt + 8) & 127;
            rh[nt] = *(const int4*)(bp + sp * 2048);
            rl[nt] = *(const int4*)(bp + sp * 2048 + 1024);
            acc[0][nt] = __builtin_amdgcn_mfma_f32_16x16x32_bf16(ah0, ubh.b, acc[0][nt], 0, 0, 0);
            acc[0][nt] = __builtin_amdgcn_mfma_f32_16x16x32_bf16(al0, ubh.b, acc[0][nt], 0, 0, 0);
            acc[0][nt] = __builtin_amdgcn_mfma_f32_16x16x32_bf16(ah0, ubl.b, acc[0][nt], 0, 0, 0);
            acc[1][nt] = __builtin_amdgcn_mfma_f32_16x16x32_bf16(ah1, ubh.b, acc[1][nt], 0, 0, 0);
            acc[1][nt] = __builtin_amdgcn_mfma_f32_16x16x32_bf16(al1, ubh.b, acc[1][nt], 0, 0, 0);
            acc[1][nt] = __builtin_amdgcn_mfma_f32_16x16x32_bf16(ah1, ubl.b, acc[1][nt], 0, 0, 0);
        }
    }
    __syncthreads();

    #pragma unroll
    for (int tg = 0; tg < 2; tg++)
        #pragma unroll
        for (int nt = 0; nt < 8; nt++)
            #pragma unroll
            for (int r = 0; r < 4; r++) {
                int t = tg * 16 + lh * 4 + r;
                int c = wid * 128 + nt * 16 + l15;
                sS[t * SUB + (c ^ (lh << 3))] = acc[tg][nt][r];
            }
    __syncthreads();

    for (int v = 0; v < 8; v++) {
        const int t   = wid * 8 + v;
        const int tok = tok0 + t;
        const int hsh = ((t >> 2) & 3) << 3;

        float sv[8];
        #pragma unroll
        for (int j = 0; j < 8; j++) sv[j] = sS[t * SUB + ((lane + 64 * j) ^ hsh)];

        float m = sv[0];
        #pragma unroll
        for (int j = 1; j < 8; j++) m = fmaxf(m, sv[j]);
        #pragma unroll
        for (int off = 32; off > 0; off >>= 1) m = fmaxf(m, __shfl_xor(m, off));

        auto wave_cnt = [&](float tau) -> int {
            int c = 0;
            #pragma unroll
            for (int j = 0; j < 8; j++)
                c += __popcll(__ballot(sv[j] > tau));
            return c;
        };

        float lo = m - 0.5f, hi = m;
        while (wave_cnt(lo) < 9) lo -= 0.5f;
        for (int it = 0; it < 14; it++) {
            float mid = 0.5f * (lo + hi);
            if (wave_cnt(mid) >= 9) lo = mid; else hi = mid;
        }
        int ch8 = wave_cnt(hi);

        float v8 = 1e30f, v9 = -1e30f;
        #pragma unroll
        for (int j = 0; j < 8; j++) {
            bool sel = sv[j] > hi;
            v8 = sel ? fminf(v8, sv[j]) : v8;
            v9 = sel ? v9 : fmaxf(v9, sv[j]);
        }
        #pragma unroll
        for (int off = 32; off > 0; off >>= 1) {
            v8 = fminf(v8, __shfl_xor(v8, off));
            v9 = fmaxf(v9, __shfl_xor(v9, off));
        }

        if (ch8 == 8 && (v8 - v9) > 6e-5f) {
            int base = 0;
            #pragma unroll
            for (int j = 0; j < 8; j++) {
                unsigned long long mk = __ballot(sv[j] > hi);
                if (sv[j] > hi) {
                    int pos = base + __popcll(mk & ((1ULL << lane) - 1ULL));
                    tk_idx[((size_t)tok * 2 + hf) * TOPK + pos] = lane + 64 * j;
                    tk_val[((size_t)tok * 2 + hf) * TOPK + pos] = sv[j];
                }
                base += __popcll(mk);
            }
        } else {
            int cand[NCAND];
            #pragma unroll
            for (int r = 0; r < NCAND; r++) {
                float bv = sv[0]; int bj = 0;
                #pragma unroll
                for (int j = 1; j < 8; j++) if (sv[j] > bv) { bv = sv[j]; bj = j; }
                int bidx = lane + 64 * bj;
                #pragma unroll
                for (int off = 32; off > 0; off >>= 1) {
                    float ov = __shfl_xor(bv, off);
                    int   oi = __shfl_xor(bidx, off);
                    if (ov > bv || (ov == bv && oi < bidx)) { bv = ov; bidx = oi; }
                }
                cand[r] = bidx;
                int jj = bidx >> 6;
                if ((bidx & 63) == lane) {
                    #pragma unroll
                    for (int j = 0; j < 8; j++) if (j == jj) sv[j] = -INFINITY;
                }
            }
            double qd[8];
            #pragma unroll
            for (int j = 0; j < 8; j++)
                qd[j] = (double)query[(size_t)tok * DDIM + qoff + lane + 64 * j];
            double rv[NCAND];
            #pragma unroll
            for (int r = 0; r < NCAND; r++) {
                const float* __restrict__ crow = &cbf[(size_t)cand[r] * KDIM];
                double a = 0.0;
                #pragma unroll
                for (int j = 0; j < 8; j++)
                    a = fma(qd[j], (double)crow[lane + 64 * j], a);
                #pragma unroll
                for (int off = 32; off > 0; off >>= 1)
                    a += __shfl_xor(a, off);
                rv[r] = a;
            }
            if (lane == 0) {
                #pragma unroll
                for (int r = 0; r < NCAND; r++) {
                    int rk = 0;
                    #pragma unroll
                    for (int mm = 0; mm < NCAND; mm++)
                        if (rv[mm] > rv[r] || (rv[mm] == rv[r] && cand[mm] < cand[r])) rk++;
                    if (rk < TOPK) {
                        tk_idx[((size_t)tok * 2 + hf) * TOPK + rk] = cand[r];
                        tk_val[((size_t)tok * 2 + hf) * TOPK + rk] = (float)rv[r];
                    }
                }
            }
        }
    }
}

// ---------------------------------------------------------------------------
// Kernel 2: one wave per token. softmax(8)x2 -> 64 weighted value rows.
// ---------------------------------------------------------------------------
__global__ __launch_bounds__(256)
void gather_kernel(const float* __restrict__ values,
                   const int*   __restrict__ tk_idx,
                   const float* __restrict__ tk_val,
                   float* __restrict__ out)
{
    const int tid  = threadIdx.x;
    const int lane = tid & 63;
    const int tok  = blockIdx.x * 4 + (tid >> 6);

    const int b1 = (tok * 2 + 0) * TOPK;
    const int b2 = (tok * 2 + 1) * TOPK;

    float v1[8], v2[8]; int i1[8], i2[8];
    #pragma unroll
    for (int j = 0; j < 8; j++) {
        i1[j] = tk_idx[b1 + j]; v1[j] = tk_val[b1 + j];
        i2[j] = tk_idx[b2 + j]; v2[j] = tk_val[b2 + j];
    }

    float m1 = v1[0], m2 = v2[0];
    #pragma unroll
    for (int j = 1; j < 8; j++) { m1 = fmaxf(m1, v1[j]); m2 = fmaxf(m2, v2[j]); }

    float w1[8], w2[8], s1 = 0.f, s2 = 0.f;
    #pragma unroll
    for (int j = 0; j < 8; j++) {
        w1[j] = expf(v1[j] - m1); s1 += w1[j];
        w2[j] = expf(v2[j] - m2); s2 += w2[j];
    }
    const float inv1 = 1.f / s1, inv2 = 1.f / s2;
    #pragma unroll
    for (int j = 0; j < 8; j++) { w1[j] *= inv1; w2[j] *= inv2; }

    float2 accA = make_float2(0.f, 0.f), accB = make_float2(0.f, 0.f);
    #pragma unroll
    for (int i = 0; i < 8; i++) {
        const int rb = i1[i] * SUB;
        const float wi = w1[i];
        #pragma unroll
        for (int j = 0; j < 8; j += 2) {
            const float wa = wi * w2[j];
            const float wb = wi * w2[j + 1];
            const float* __restrict__ ra = values + (size_t)(rb + i2[j])     * VDIM;
            const float* __restrict__ rbp = values + (size_t)(rb + i2[j + 1]) * VDIM;
            float2 ta = *(const float2*)&ra[lane * 2];
            float2 tb = *(const float2*)&rbp[lane * 2];
            accA.x = fmaf(wa, ta.x, accA.x);
            accA.y = fmaf(wa, ta.y, accA.y);
            accB.x = fmaf(wb, tb.x, accB.x);
            accB.y = fmaf(wb, tb.y, accB.y);
        }
    }
    float2 acc = make_float2(accA.x + accB.x, accA.y + accB.y);
    *(float2*)&out[(size_t)tok * VDIM + lane * 2] = acc;
}

extern "C" void kernel_launch(void* const* d_in, const int* in_sizes, int n_in,
                              void* d_out, int out_size, void* d_ws, size_t ws_size,
                              hipStream_t stream) {
    const float* query  = (const float*)d_in[0];
    const float* cb1    = (const float*)d_in[1];
    const float* cb2    = (const float*)d_in[2];
    const float* values = (const float*)d_in[3];
    float* out = (float*)d_out;

    char* ws = (char*)d_ws;
    int*   tk_idx = (int*)ws;                    // 1 MB
    float* tk_val = (float*)(ws + (1u << 20));   // 1 MB
    char*  Bp     = ws + (2u << 20);             // 2 MB packed hi/lo B stream
    float* scores = (float*)(ws + (4u << 20));   // 64 MB fp32 [16384][1024]

    cvt_bfrag<<<256, 256, 0, stream>>>(cb1, cb2, Bp);

    if (ws_size >= (68u << 20)) {
        dim3 g1(NTOK / 16, 2);
        score_gemm<<<g1, 256, 0, stream>>>(query, Bp, scores);
        topk_kernel<<<NTOK * 2 / 4, 256, 0, stream>>>(scores, query, cb1, cb2,
                                                      tk_idx, tk_val);
    } else {
        dim3 g1(NTOK / 32, 2);
        score_topk_fused<<<g1, 256, 0, stream>>>(query, cb1, cb2, Bp, tk_idx, tk_val);
    }
    gather_kernel<<<NTOK / 4, 256, 0, stream>>>(values, tk_idx, tk_val, out);
}

// Round 8
// 252.317 us; speedup vs baseline: 1.0013x; 1.0013x over previous
//
#include <hip/hip_runtime.h>
#include <hip/hip_bf16.h>
#include <math.h>

#define NTOK 16384
#define DDIM 1024
#define HALF 512
#define SUB  512
#define KDIM 512
#define TOPK 8
#define NCAND 16
#define VDIM 128
#define TMB 64          // tokens per block (score kernel)

typedef __attribute__((ext_vector_type(8))) short bf16x8;
typedef __attribute__((ext_vector_type(4))) float f32x4;

static __device__ __forceinline__ unsigned short f2bf(float x) {
    union { float f; unsigned u; } v; v.f = x;
    unsigned r = v.u + 0x7FFF + ((v.u >> 16) & 1);   // RNE
    return (unsigned short)(r >> 16);
}

static __device__ __forceinline__ void split_bf(float x, unsigned short& h, unsigned short& l) {
    h = f2bf(x);
    union { unsigned u; float f; } hv; hv.u = ((unsigned)h) << 16;
    l = f2bf(x - hv.f);
}

// ---------------------------------------------------------------------------
// Kernel 0: codebooks -> packed hi/lo bf16 MFMA-B fragments:
//   frag-pair fp = hf*512 + w*64 + kc*4 + nt  (w = 8-wave cand slice of 64)
//   elem: n = w*64 + nt*16 + (lane&15), k = kc*32 + (lane>>4)*8 + j
//   Bp[fp*2048 + lane*16] = hi frag, +1024 = lo frag.
// ---------------------------------------------------------------------------
__global__ __launch_bounds__(256)
void cvt_bfrag(const float* __restrict__ cb1, const float* __restrict__ cb2,
               char* __restrict__ Bp)
{
    int fid  = blockIdx.x * 256 + threadIdx.x;   // 0..65535
    int lane = fid & 63;
    int fp   = fid >> 6;                         // 0..1023
    int nt   = fp & 3;
    int kc   = (fp >> 2) & 15;
    int w    = (fp >> 6) & 7;
    int hf   = (fp >> 9) & 1;
    const float* cb = hf ? cb2 : cb1;
    int n  = w * 64 + nt * 16 + (lane & 15);
    int kb = kc * 32 + (lane >> 4) * 8;
    const float* src = cb + (size_t)n * KDIM + kb;
    float4 f0 = *(const float4*)src;
    float4 f1 = *(const float4*)(src + 4);
    unsigned short hh[8], ll[8];
    split_bf(f0.x, hh[0], ll[0]); split_bf(f0.y, hh[1], ll[1]);
    split_bf(f0.z, hh[2], ll[2]); split_bf(f0.w, hh[3], ll[3]);
    split_bf(f1.x, hh[4], ll[4]); split_bf(f1.y, hh[5], ll[5]);
    split_bf(f1.z, hh[6], ll[6]); split_bf(f1.w, hh[7], ll[7]);
    *(int4*)(Bp + (size_t)fp * 2048 + lane * 16)        = *(const int4*)hh;
    *(int4*)(Bp + (size_t)fp * 2048 + lane * 16 + 1024) = *(const int4*)ll;
}

// ---------------------------------------------------------------------------
// Kernel 1: fused score+topk. 512 threads (8 waves), 64 tokens, one half.
//   Wave = 64-cand slice (4 nt tiles), all 64 tokens (4 tok-rows).
//   A: fp32->bf16 hi/lo fragments in 128 KB LDS (read via ds_read_b128,
//      costs no L1 bandwidth). B: streamed global->reg, in-place ring,
//      term-major nt-pair schedule (same-acc dist 8, reload lookahead >=24).
//   Phase 2: 2 rounds x 32-token LDS dump (overlays dead A) + proven
//   ballot-bisect top-8 + rare fp64 slow path.
// ---------------------------------------------------------------------------
__global__ __launch_bounds__(512, 2)
void score_topk_fused(const float* __restrict__ query,
                      const float* __restrict__ cb1f,
                      const float* __restrict__ cb2f,
                      const char* __restrict__ Bp,
                      int*   __restrict__ tk_idx,
                      float* __restrict__ tk_val)
{
    __shared__ char smem[131072];
    // GEMM phase: A frags [kc16][tr4][hl2][lane64 * 16B]
    // phase 2:    fp32 scores sS[32][512] overlays first 64 KB
    float* sS = (float*)smem;

    const int tid  = threadIdx.x;
    const int hf   = blockIdx.y;
    const int tok0 = blockIdx.x * TMB;
    const float* __restrict__ cbf = hf ? cb2f : cb1f;
    const int qoff = hf * HALF;

    const int lane = tid & 63;
    const int wid  = tid >> 6;          // 0..7 = cand slice
    const int l15  = lane & 15;
    const int lh   = lane >> 4;

    // ---- stage A: 64 tok x 512 k -> split-bf16 fragments in LDS ----
    {
        const int tok = tid >> 3;        // 0..63
        const int ks  = tid & 7;
        const int tr  = tok >> 4;
        const int lb  = tok & 15;
        const float* qrow = query + (size_t)(tok0 + tok) * DDIM + qoff;
        #pragma unroll
        for (int it = 0; it < 4; it++) {
            const int k = ks * 64 + it * 16;
            float4 f0 = *(const float4*)(qrow + k);
            float4 f1 = *(const float4*)(qrow + k + 4);
            float4 f2 = *(const float4*)(qrow + k + 8);
            float4 f3 = *(const float4*)(qrow + k + 12);
            unsigned short hh[16], ll[16];
            split_bf(f0.x, hh[0],  ll[0]);  split_bf(f0.y, hh[1],  ll[1]);
            split_bf(f0.z, hh[2],  ll[2]);  split_bf(f0.w, hh[3],  ll[3]);
            split_bf(f1.x, hh[4],  ll[4]);  split_bf(f1.y, hh[5],  ll[5]);
            split_bf(f1.z, hh[6],  ll[6]);  split_bf(f1.w, hh[7],  ll[7]);
            split_bf(f2.x, hh[8],  ll[8]);  split_bf(f2.y, hh[9],  ll[9]);
            split_bf(f2.z, hh[10], ll[10]); split_bf(f2.w, hh[11], ll[11]);
            split_bf(f3.x, hh[12], ll[12]); split_bf(f3.y, hh[13], ll[13]);
            split_bf(f3.z, hh[14], ll[14]); split_bf(f3.w, hh[15], ll[15]);
            const int kc  = k >> 5;
            const int lw0 = lb + ((k & 31) >> 3) * 16;   // frag lane for elems 0-7
            char* base = smem + kc * 8192 + tr * 2048;
            *(int4*)(base + lw0 * 16)              = *(const int4*)(hh);
            *(int4*)(base + lw0 * 16 + 256)        = *(const int4*)(hh + 8);
            *(int4*)(base + 1024 + lw0 * 16)       = *(const int4*)(ll);
            *(int4*)(base + 1024 + lw0 * 16 + 256) = *(const int4*)(ll + 8);
        }
    }
    __syncthreads();

    // ---- B stream: per-wave 128 KB slice, in-place 8-slot ring ----
    const char* bp = Bp + (size_t)(hf * 8 + wid) * 131072 + lane * 16;

    int4 ring[8];                        // [nt*2 + hl] for current kc
    #pragma unroll
    for (int nt = 0; nt < 4; nt++) {
        ring[nt * 2]     = *(const int4*)(bp + nt * 2048);
        ring[nt * 2 + 1] = *(const int4*)(bp + nt * 2048 + 1024);
    }

    f32x4 acc[4][4];
    #pragma unroll
    for (int tr = 0; tr < 4; tr++)
        #pragma unroll
        for (int nt = 0; nt < 4; nt++) acc[tr][nt] = (f32x4){0.f, 0.f, 0.f, 0.f};

    for (int kc = 0; kc < 16; kc++) {
        bf16x8 ah[4], al[4];
        #pragma unroll
        for (int tr = 0; tr < 4; tr++) {
            ah[tr] = *(const bf16x8*)(smem + kc * 8192 + tr * 2048 + lane * 16);
            al[tr] = *(const bf16x8*)(smem + kc * 8192 + tr * 2048 + 1024 + lane * 16);
        }
        const int nb = ((kc + 1) & 15) * 4;          // next kc's nt base
        #pragma unroll
        for (int ntp = 0; ntp < 4; ntp += 2) {
            union { int4 i; bf16x8 b; } b0h, b1h, b0l, b1l;
            b0h.i = ring[ntp * 2];     b0l.i = ring[ntp * 2 + 1];
            b1h.i = ring[ntp * 2 + 2]; b1l.i = ring[ntp * 2 + 3];
            // T1: hi x hi
            #pragma unroll
            for (int tr = 0; tr < 4; tr++)
                acc[tr][ntp]   = __builtin_amdgcn_mfma_f32_16x16x32_bf16(ah[tr], b0h.b, acc[tr][ntp],   0, 0, 0);
            #pragma unroll
            for (int tr = 0; tr < 4; tr++)
                acc[tr][ntp+1] = __builtin_amdgcn_mfma_f32_16x16x32_bf16(ah[tr], b1h.b, acc[tr][ntp+1], 0, 0, 0);
            // reload hi pair for next kc, then T3: lo x hi
            ring[ntp * 2]     = *(const int4*)(bp + (nb + ntp) * 2048);
            ring[ntp * 2 + 2] = *(const int4*)(bp + (nb + ntp + 1) * 2048);
            #pragma unroll
            for (int tr = 0; tr < 4; tr++)
                acc[tr][ntp]   = __builtin_amdgcn_mfma_f32_16x16x32_bf16(al[tr], b0h.b, acc[tr][ntp],   0, 0, 0);
            #pragma unroll
            for (int tr = 0; tr < 4; tr++)
                acc[tr][ntp+1] = __builtin_amdgcn_mfma_f32_16x16x32_bf16(al[tr], b1h.b, acc[tr][ntp+1], 0, 0, 0);
            // reload lo pair, then T2: hi x lo
            ring[ntp * 2 + 1] = *(const int4*)(bp + (nb + ntp) * 2048 + 1024);
            ring[ntp * 2 + 3] = *(const int4*)(bp + (nb + ntp + 1) * 2048 + 1024);
            #pragma unroll
            for (int tr = 0; tr < 4; tr++)
                acc[tr][ntp]   = __builtin_amdgcn_mfma_f32_16x16x32_bf16(ah[tr], b0l.b, acc[tr][ntp],   0, 0, 0);
            #pragma unroll
            for (int tr = 0; tr < 4; tr++)
                acc[tr][ntp+1] = __builtin_amdgcn_mfma_f32_16x16x32_bf16(ah[tr], b1l.b, acc[tr][ntp+1], 0, 0, 0);
        }
    }
    __syncthreads();   // all A reads done; sS may overwrite

    // ---- phase 2: two rounds of 32 tokens ----
    for (int round = 0; round < 2; round++) {
        // dump: C/D layout row=(lane>>4)*4+r, col=lane&15
        #pragma unroll
        for (int tr2 = 0; tr2 < 2; tr2++)
            #pragma unroll
            for (int nt = 0; nt < 4; nt++)
                #pragma unroll
                for (int r = 0; r < 4; r++) {
                    int t = tr2 * 16 + lh * 4 + r;               // 0..31
                    int c = wid * 64 + nt * 16 + l15;
                    sS[t * SUB + (c ^ (lh << 3))] = acc[round * 2 + tr2][nt][r];
                }
        __syncthreads();

        // each wave: 4 tokens
        for (int v = 0; v < 4; v++) {
            const int t   = wid * 4 + v;                         // 0..31
            const int tok = tok0 + round * 32 + t;
            const int hsh = ((t >> 2) & 3) << 3;

            float sv[8];
            #pragma unroll
            for (int j = 0; j < 8; j++) sv[j] = sS[t * SUB + ((lane + 64 * j) ^ hsh)];

            float m = sv[0];
            #pragma unroll
            for (int j = 1; j < 8; j++) m = fmaxf(m, sv[j]);
            #pragma unroll
            for (int off = 32; off > 0; off >>= 1) m = fmaxf(m, __shfl_xor(m, off));

            auto wave_cnt = [&](float tau) -> int {
                int c = 0;
                #pragma unroll
                for (int j = 0; j < 8; j++)
                    c += __popcll(__ballot(sv[j] > tau));
                return c;
            };

            float lo = m - 0.5f, hi = m;
            while (wave_cnt(lo) < 9) lo -= 0.5f;
            for (int it = 0; it < 14; it++) {
                float mid = 0.5f * (lo + hi);
                if (wave_cnt(mid) >= 9) lo = mid; else hi = mid;
            }
            int ch8 = wave_cnt(hi);

            float v8 = 1e30f, v9 = -1e30f;
            #pragma unroll
            for (int j = 0; j < 8; j++) {
                bool sel = sv[j] > hi;
                v8 = sel ? fminf(v8, sv[j]) : v8;
                v9 = sel ? v9 : fmaxf(v9, sv[j]);
            }
            #pragma unroll
            for (int off = 32; off > 0; off >>= 1) {
                v8 = fminf(v8, __shfl_xor(v8, off));
                v9 = fmaxf(v9, __shfl_xor(v9, off));
            }

            if (ch8 == 8 && (v8 - v9) > 6e-5f) {
                int base = 0;
                #pragma unroll
                for (int j = 0; j < 8; j++) {
                    unsigned long long mk = __ballot(sv[j] > hi);
                    if (sv[j] > hi) {
                        int pos = base + __popcll(mk & ((1ULL << lane) - 1ULL));
                        tk_idx[((size_t)tok * 2 + hf) * TOPK + pos] = lane + 64 * j;
                        tk_val[((size_t)tok * 2 + hf) * TOPK + pos] = sv[j];
                    }
                    base += __popcll(mk);
                }
            } else {
                // slow path (rare): coarse top-16 + fp64 rescore, exact ordering
                int cand[NCAND];
                #pragma unroll
                for (int r = 0; r < NCAND; r++) {
                    float bv = sv[0]; int bj = 0;
                    #pragma unroll
                    for (int j = 1; j < 8; j++) if (sv[j] > bv) { bv = sv[j]; bj = j; }
                    int bidx = lane + 64 * bj;
                    #pragma unroll
                    for (int off = 32; off > 0; off >>= 1) {
                        float ov = __shfl_xor(bv, off);
                        int   oi = __shfl_xor(bidx, off);
                        if (ov > bv || (ov == bv && oi < bidx)) { bv = ov; bidx = oi; }
                    }
                    cand[r] = bidx;
                    int jj = bidx >> 6;
                    if ((bidx & 63) == lane) {
                        #pragma unroll
                        for (int j = 0; j < 8; j++) if (j == jj) sv[j] = -INFINITY;
                    }
                }
                double qd[8];
                #pragma unroll
                for (int j = 0; j < 8; j++)
                    qd[j] = (double)query[(size_t)tok * DDIM + qoff + lane + 64 * j];
                double rv[NCAND];
                #pragma unroll
                for (int r = 0; r < NCAND; r++) {
                    const float* __restrict__ crow = &cbf[(size_t)cand[r] * KDIM];
                    double a = 0.0;
                    #pragma unroll
                    for (int j = 0; j < 8; j++)
                        a = fma(qd[j], (double)crow[lane + 64 * j], a);
                    #pragma unroll
                    for (int off = 32; off > 0; off >>= 1)
                        a += __shfl_xor(a, off);
                    rv[r] = a;
                }
                if (lane == 0) {
                    #pragma unroll
                    for (int r = 0; r < NCAND; r++) {
                        int rk = 0;
                        #pragma unroll
                        for (int mm = 0; mm < NCAND; mm++)
                            if (rv[mm] > rv[r] || (rv[mm] == rv[r] && cand[mm] < cand[r])) rk++;
                        if (rk < TOPK) {
                            tk_idx[((size_t)tok * 2 + hf) * TOPK + rk] = cand[r];
                            tk_val[((size_t)tok * 2 + hf) * TOPK + rk] = (float)rv[r];
                        }
                    }
                }
            }
        }
        __syncthreads();   // round 2 dump must not race round 1 reads
    }
}

// ---------------------------------------------------------------------------
// Kernel 2: one wave per token. softmax(8)x2 -> 64 weighted value rows,
// all 64 row-loads issued into registers before consumption (latency hiding).
// ---------------------------------------------------------------------------
__global__ __launch_bounds__(256)
void gather_kernel(const float* __restrict__ values,
                   const int*   __restrict__ tk_idx,
                   const float* __restrict__ tk_val,
                   float* __restrict__ out)
{
    const int tid  = threadIdx.x;
    const int lane = tid & 63;
    const int tok  = blockIdx.x * 4 + (tid >> 6);

    const int b1 = (tok * 2 + 0) * TOPK;
    const int b2 = (tok * 2 + 1) * TOPK;

    float v1[8], v2[8]; int i1[8], i2[8];
    #pragma unroll
    for (int j = 0; j < 8; j++) {
        i1[j] = tk_idx[b1 + j]; v1[j] = tk_val[b1 + j];
        i2[j] = tk_idx[b2 + j]; v2[j] = tk_val[b2 + j];
    }

    float m1 = v1[0], m2 = v2[0];
    #pragma unroll
    for (int j = 1; j < 8; j++) { m1 = fmaxf(m1, v1[j]); m2 = fmaxf(m2, v2[j]); }

    float w1[8], w2[8], s1 = 0.f, s2 = 0.f;
    #pragma unroll
    for (int j = 0; j < 8; j++) {
        w1[j] = expf(v1[j] - m1); s1 += w1[j];
        w2[j] = expf(v2[j] - m2); s2 += w2[j];
    }
    const float inv1 = 1.f / s1, inv2 = 1.f / s2;
    #pragma unroll
    for (int j = 0; j < 8; j++) { w1[j] *= inv1; w2[j] *= inv2; }

    float2 bufA[32], bufB[32];
    #pragma unroll
    for (int k = 0; k < 32; k++) {
        const int i = k >> 3, j = k & 7;
        bufA[k] = *(const float2*)(values + (size_t)(i1[i] * SUB + i2[j]) * VDIM + lane * 2);
    }
    #pragma unroll
    for (int k = 0; k < 32; k++) {
        const int i = 4 + (k >> 3), j = k & 7;
        bufB[k] = *(const float2*)(values + (size_t)(i1[i] * SUB + i2[j]) * VDIM + lane * 2);
    }

    float2 aA = make_float2(0.f, 0.f), aB = make_float2(0.f, 0.f);
    #pragma unroll
    for (int k = 0; k < 32; k++) {
        const float wa = w1[k >> 3] * w2[k & 7];
        aA.x = fmaf(wa, bufA[k].x, aA.x);
        aA.y = fmaf(wa, bufA[k].y, aA.y);
    }
    #pragma unroll
    for (int k = 0; k < 32; k++) {
        const float wb = w1[4 + (k >> 3)] * w2[k & 7];
        aB.x = fmaf(wb, bufB[k].x, aB.x);
        aB.y = fmaf(wb, bufB[k].y, aB.y);
    }
    float2 acc = make_float2(aA.x + aB.x, aA.y + aB.y);
    *(float2*)&out[(size_t)tok * VDIM + lane * 2] = acc;
}

extern "C" void kernel_launch(void* const* d_in, const int* in_sizes, int n_in,
                              void* d_out, int out_size, void* d_ws, size_t ws_size,
                              hipStream_t stream) {
    const float* query  = (const float*)d_in[0];
    const float* cb1    = (const float*)d_in[1];
    const float* cb2    = (const float*)d_in[2];
    const float* values = (const float*)d_in[3];
    float* out = (float*)d_out;

    char* ws = (char*)d_ws;
    int*   tk_idx = (int*)ws;                    // 1 MB
    float* tk_val = (float*)(ws + (1u << 20));   // 1 MB
    char*  Bp     = ws + (2u << 20);             // 2 MB packed hi/lo B fragments

    cvt_bfrag<<<256, 256, 0, stream>>>(cb1, cb2, Bp);
    dim3 g1(NTOK / TMB, 2);
    score_topk_fused<<<g1, 512, 0, stream>>>(query, cb1, cb2, Bp, tk_idx, tk_val);
    gather_kernel<<<NTOK / 4, 256, 0, stream>>>(values, tk_idx, tk_val, out);
}